// Round 6
// baseline (412.859 us; speedup 1.0000x reference)
//
#include <hip/hip_runtime.h>

#define FDIM 128  // feature dim == hidden dim

typedef __attribute__((ext_vector_type(8))) short short8;   // 8 bf16 (4 VGPRs)
typedef __attribute__((ext_vector_type(4))) float f32x4;    // MFMA accumulator

__device__ inline unsigned short f2bf(float f) {  // round-to-nearest-even
    unsigned int u = __float_as_uint(f);
    unsigned int r = u + 0x7FFFu + ((u >> 16) & 1u);
    return (unsigned short)(r >> 16);
}
__device__ inline float bf2f(unsigned short b) {
    return __uint_as_float((unsigned int)b << 16);
}
__device__ inline void bf8_fma(short8 v, float c, float* acc) {
#pragma unroll
    for (int k = 0; k < 8; ++k)
        acc[k] = fmaf(bf2f(((const unsigned short*)&v)[k]), c, acc[k]);
}

// ---------------------------------------------------------------------------
// 1) heterogeneous pre-pass: blocks [0,statBlocks) = column sum/sumsq partials
//    (BW-bound sweep of x) + bf16 cast of x written to xbf (aliases bufB,
//    dead until agg_gemm2) so gemm1 reads 51 MB instead of 102 MB;
//    blocks >= statBlocks = dst-degree atomics (latency-bound) — merged so
//    the two run concurrently.
__global__ __launch_bounds__(256) void pre_combo(const float* __restrict__ x, int N,
                                                 float* __restrict__ partials, int statBlocks,
                                                 const int* __restrict__ dst, int E,
                                                 int* __restrict__ cnt,
                                                 unsigned short* __restrict__ xbf) {
    if ((int)blockIdx.x >= statBlocks) {
        int e = (blockIdx.x - statBlocks) * 256 + threadIdx.x;
        if (e < E) atomicAdd(&cnt[dst[e]], 1);
        return;
    }
    const int c4 = threadIdx.x & 31;
    const int rg = threadIdx.x >> 5;
    float4 s = make_float4(0.f, 0.f, 0.f, 0.f);
    float4 q = make_float4(0.f, 0.f, 0.f, 0.f);
    for (long r = (long)blockIdx.x * 8 + rg; r < N; r += (long)statBlocks * 8) {
        float4 v = ((const float4*)x)[r * 32 + c4];
        s.x += v.x; s.y += v.y; s.z += v.z; s.w += v.w;
        q.x += v.x * v.x; q.y += v.y * v.y; q.z += v.z * v.z; q.w += v.w * v.w;
        ushort4 p;
        p.x = f2bf(v.x); p.y = f2bf(v.y); p.z = f2bf(v.z); p.w = f2bf(v.w);
        ((ushort4*)xbf)[r * 32 + c4] = p;
    }
    __shared__ float red[8][32][8];
    float* p = red[rg][c4];
    p[0] = s.x; p[1] = s.y; p[2] = s.z; p[3] = s.w;
    p[4] = q.x; p[5] = q.y; p[6] = q.z; p[7] = q.w;
    __syncthreads();
    if (rg == 0) {
#pragma unroll
        for (int g = 1; g < 8; ++g) {
            const float* o = red[g][c4];
#pragma unroll
            for (int j = 0; j < 8; ++j) red[0][c4][j] += o[j];
        }
        const float* r0 = red[0][c4];
        float* out = &partials[(size_t)blockIdx.x * 256];
        ((float4*)out)[c4] = make_float4(r0[0], r0[1], r0[2], r0[3]);
        ((float4*)(out + 128))[c4] = make_float4(r0[4], r0[5], r0[6], r0[7]);
    }
}

// ---------------------------------------------------------------------------
// 2) mid_combo: blocks [0, offsBlocks) = per-node edge-range scan + dinv;
//    blocks offsBlocks..+8 = W1 stats-slice reduce + scaled transpose + bias0;
//    blocks +8..+16 = W2 transpose.
__global__ __launch_bounds__(256) void mid_combo(const int* __restrict__ cnt, int N,
                                                 int* __restrict__ start,
                                                 int* __restrict__ wcur,
                                                 int* __restrict__ counter,
                                                 float* __restrict__ dinv,
                                                 const float* __restrict__ partials,
                                                 int nblk, int offsBlocks,
                                                 const float* __restrict__ W1,
                                                 const float* __restrict__ W2,
                                                 unsigned short* __restrict__ WT1,
                                                 unsigned short* __restrict__ WT2,
                                                 float* __restrict__ bias0) {
    const int tid = threadIdx.x;
    if ((int)blockIdx.x < offsBlocks) {
        __shared__ int sh[256];
        __shared__ int base;
        int i = blockIdx.x * 256 + tid;
        int v = (i < N) ? cnt[i] : 0;
        sh[tid] = v;
        __syncthreads();
        for (int off = 1; off < 256; off <<= 1) {
            int t = (tid >= off) ? sh[tid - off] : 0;
            __syncthreads();
            sh[tid] += t;
            __syncthreads();
        }
        if (tid == 255) base = atomicAdd(counter, sh[255]);
        __syncthreads();
        int excl = base + sh[tid] - v;
        if (i < N) {
            start[i] = excl;
            wcur[i] = excl;
            dinv[i] = rsqrtf((float)v + 1.0f);
        }
        return;
    }
    const int b = blockIdx.x - offsBlocks;  // 0..15
    const int h = tid & 127;
    const int seg = tid >> 7;  // 0,1
    if (b < 8) {
        // reduce this block's 32-col slice: 16 sum cols + 16 sumsq cols
        __shared__ float red[32][32];  // [rowgroup][localcol] 4 KB
        __shared__ float scol[32], mean_sh[16], rstd_sh[16];
        const int rg = tid >> 3;      // 0..31
        const int f = tid & 7;        // 0..7
        const int colbase = (f < 4) ? (b * 16 + f * 4) : (128 + b * 16 + (f - 4) * 4);
        float4 a = make_float4(0.f, 0.f, 0.f, 0.f);
        for (int row = rg; row < nblk; row += 32) {
            float4 v = *(const float4*)&partials[(size_t)row * 256 + colbase];
            a.x += v.x; a.y += v.y; a.z += v.z; a.w += v.w;
        }
        *(float4*)&red[rg][f * 4] = a;
        __syncthreads();
        if (tid < 32) {
            float s = 0.f;
#pragma unroll
            for (int r = 0; r < 32; ++r) s += red[r][tid];
            scol[tid] = s;
        }
        __syncthreads();
        if (tid < 16) {
            float m = scol[tid] / (float)N;
            float var = (scol[16 + tid] - (float)N * m * m) / (float)(N - 1);
            mean_sh[tid] = m;
            rstd_sh[tid] = rsqrtf(var);
        }
        __syncthreads();
        float acc = 0.f;
#pragma unroll
        for (int jj = 0; jj < 8; ++jj) {
            int jl = seg * 8 + jj;
            int j2 = b * 16 + jl;
            float w = W1[j2 * FDIM + h] * rstd_sh[jl];
            WT1[h * FDIM + j2] = f2bf(w);
            acc += mean_sh[jl] * w;
        }
        unsafeAtomicAdd(&bias0[h], -acc);
    } else {
#pragma unroll
        for (int jj = 0; jj < 8; ++jj) {
            int j2 = (b - 8) * 16 + seg * 8 + jj;
            WT2[h * FDIM + j2] = f2bf(W2[j2 * FDIM + h]);
        }
    }
}

// ---------------------------------------------------------------------------
// 3) GEMM1 + edge-bucketing merged. MFMA operands SWAPPED (W-frag as A,
//    x-frag as B) so D comes out transposed: m=h-within-tile (quad*4+reg),
//    n=x-row (lane&15). Epilogue = 8 contiguous short4 stores per lane.
//    W stays in LDS (round-2 lesson: W-frags from global put an L2 hit on
//    every MFMA's critical path — load latency, not occupancy, is binding).
//    A is read pre-cast bf16 (xbf from pre_combo).
__global__ __launch_bounds__(256) void gemm1_fill(const unsigned short* __restrict__ A,
                                                  const unsigned short* __restrict__ WT,
                                                  const float* __restrict__ bias,
                                                  unsigned short* __restrict__ C, int M,
                                                  int gemmBlocks,
                                                  const int* __restrict__ src,
                                                  const int* __restrict__ dst,
                                                  const float* __restrict__ dinv,
                                                  int* __restrict__ wcur,
                                                  int2* __restrict__ edata, int E) {
    const int tid = threadIdx.x;
    if ((int)blockIdx.x >= gemmBlocks) {
        int e = (blockIdx.x - gemmBlocks) * 256 + tid;
        if (e < E) {
            int s = src[e], d = dst[e];
            int pos = atomicAdd(&wcur[d], 1);
            edata[pos] = make_int2(s, __float_as_int(dinv[s] * dinv[d]));
        }
        return;
    }
    constexpr int LDA = 136;
    __shared__ unsigned short Alds[64 * LDA];
    __shared__ unsigned short Wlds[FDIM * LDA];
    const int row0 = blockIdx.x * 64;

    for (int i = tid; i < FDIM * 16; i += 256) {
        int r = i >> 4, g = i & 15;
        *(int4*)&Wlds[r * LDA + g * 8] = *(const int4*)&WT[r * FDIM + g * 8];
    }
    for (int i = tid; i < 64 * 16; i += 256) {
        int r = i >> 4, g = i & 15;
        int row = row0 + r;
        int4 v = make_int4(0, 0, 0, 0);
        if (row < M) v = *(const int4*)&A[(size_t)row * FDIM + g * 8];
        *(int4*)&Alds[r * LDA + g * 8] = v;
    }
    __syncthreads();

    const int lane = tid & 63;
    const int wave = tid >> 6;
    const int m16 = lane & 15;
    const int quad = lane >> 4;

    f32x4 acc[8];
#pragma unroll
    for (int t = 0; t < 8; ++t) acc[t] = (f32x4){0.f, 0.f, 0.f, 0.f};

    const unsigned short* Abase = &Alds[(wave * 16 + m16) * LDA + quad * 8];
    const unsigned short* Wbase = &Wlds[m16 * LDA + quad * 8];
#pragma unroll
    for (int s = 0; s < 4; ++s) {
        short8 a = *(const short8*)&Abase[s * 32];
#pragma unroll
        for (int t = 0; t < 8; ++t) {
            short8 b = *(const short8*)&Wbase[t * 16 * LDA + s * 32];
            // swapped: W-frag is the A operand -> D[m=h][n=x-row]
            acc[t] = __builtin_amdgcn_mfma_f32_16x16x32_bf16(b, a, acc[t], 0, 0, 0);
        }
    }

    // epilogue: lane's x-row = m16 (fixed); per t a contiguous short4 at
    // col t*16 + quad*4.
    const int r = row0 + wave * 16 + m16;
    if (r < M) {
#pragma unroll
        for (int t = 0; t < 8; ++t) {
            ushort4 o;
            o.x = f2bf(acc[t][0] + bias[t * 16 + quad * 4 + 0]);
            o.y = f2bf(acc[t][1] + bias[t * 16 + quad * 4 + 1]);
            o.z = f2bf(acc[t][2] + bias[t * 16 + quad * 4 + 2]);
            o.w = f2bf(acc[t][3] + bias[t * 16 + quad * 4 + 3]);
            *(ushort4*)&C[(size_t)r * FDIM + t * 16 + quad * 4] = o;
        }
    }
}

// ---------------------------------------------------------------------------
// 4) layer-1 aggregation FUSED with the layer-2 GEMM. Gather = branch-free
//    8-deep batch, FORCED with asm memory fences (rounds 4-5 lesson: the
//    register-pressure-greedy scheduler sinks each row load to just before
//    its FMA, re-serializing the chain — VGPR stayed at 44). The fence pins
//    all 8 loads before any use: one vmcnt drain per batch instead of ~deg.
//    Loads unconditional with clamped indices (dups -> same addr -> L1 hit);
//    correctness via zeroed coefficient (fma(x,0,acc) bitwise identity).
//    Issue order: self-row/bias/dinv first (their use waits only their own
//    vmcnt slot), then e-batch, then u-batch.
__global__ __launch_bounds__(256) void agg_gemm2(const unsigned short* __restrict__ xw,
                                                 const float* __restrict__ dinv,
                                                 const int* __restrict__ start,
                                                 const int* __restrict__ cnt,
                                                 const int2* __restrict__ edata,
                                                 const float* __restrict__ bvec,
                                                 const unsigned short* __restrict__ WT2,
                                                 unsigned short* __restrict__ out,
                                                 int N) {
    const int base = blockIdx.x * 16;
    const int node = base + (threadIdx.x >> 4);
    const int l8 = threadIdx.x & 15;  // 8-col group
    const bool active = node < N;     // NO early return: __syncthreads below
    const int nidx = active ? node : (N - 1);

    // exposure 1: all node-scalar + self-row loads issued together
    const int j = start[nidx];
    const int c = active ? cnt[nidx] : 0;
    float dv = dinv[nidx];
    float4 b0 = ((const float4*)bvec)[l8 * 2];
    float4 b1v = ((const float4*)bvec)[l8 * 2 + 1];
    short8 sv = *(const short8*)&xw[(size_t)nidx * FDIM + l8 * 8];

    const int jb = (c > 0) ? j : 0;       // safe base when deg==0
    const int cm = (c > 0) ? c - 1 : 0;   // clamp offset

    // exposure 2: edata batch (contiguous <=64B region), pinned by fence
    int2 e[8];
#pragma unroll
    for (int k = 0; k < 8; ++k) e[k] = edata[jb + min(k, cm)];
    asm volatile("" ::: "memory");  // pin: all e-loads issued before any use

    float d2 = dv * dv;
    float acc[8] = {b0.x, b0.y, b0.z, b0.w, b1v.x, b1v.y, b1v.z, b1v.w};
    bf8_fma(sv, d2, acc);

    // exposure 3: row batch, pinned by fence
    short8 u[8];
#pragma unroll
    for (int k = 0; k < 8; ++k)
        u[k] = *(const short8*)&xw[(size_t)e[k].x * FDIM + l8 * 8];
    asm volatile("" ::: "memory");  // pin: all u-loads issued before any FMA

#pragma unroll
    for (int k = 0; k < 8; ++k) {
        float ck = (k < c) ? __int_as_float(e[k].y) : 0.f;
        bf8_fma(u[k], ck, acc);
    }

    for (int k = 8; k < c; ++k) {  // rare: deg > 8
        int2 ed = edata[j + k];
        short8 uu = *(const short8*)&xw[(size_t)ed.x * FDIM + l8 * 8];
        bf8_fma(uu, __int_as_float(ed.y), acc);
    }

    // relu + stage the 16x128 h1 tile (bf16) for the MFMA
    constexpr int LDH = 136;
    __shared__ unsigned short hlds[16 * LDH];  // 4.25 KiB
    {
        ushort4 o0, o1;
        if (active) {
            o0.x = f2bf(fmaxf(acc[0], 0.f)); o0.y = f2bf(fmaxf(acc[1], 0.f));
            o0.z = f2bf(fmaxf(acc[2], 0.f)); o0.w = f2bf(fmaxf(acc[3], 0.f));
            o1.x = f2bf(fmaxf(acc[4], 0.f)); o1.y = f2bf(fmaxf(acc[5], 0.f));
            o1.z = f2bf(fmaxf(acc[6], 0.f)); o1.w = f2bf(fmaxf(acc[7], 0.f));
        } else {
            o0.x = 0; o0.y = 0; o0.z = 0; o0.w = 0;
            o1.x = 0; o1.y = 0; o1.z = 0; o1.w = 0;
        }
        unsigned short* hp = &hlds[(threadIdx.x >> 4) * LDH + l8 * 8];
        *(ushort4*)hp = o0;
        *(ushort4*)(hp + 4) = o1;
    }
    __syncthreads();

    // swapped-operand MFMA: D[m=h][n=node]; wave w owns h-cols [w*32, w*32+32)
    const int lane = threadIdx.x & 63;
    const int wave = threadIdx.x >> 6;
    const int m16 = lane & 15;
    const int quad = lane >> 4;
    f32x4 c0 = (f32x4){0.f, 0.f, 0.f, 0.f};
    f32x4 c1 = (f32x4){0.f, 0.f, 0.f, 0.f};
    const unsigned short* Abase = &hlds[m16 * LDH + quad * 8];
    const unsigned short* Wg = &WT2[(size_t)(wave * 32 + m16) * FDIM + quad * 8];
#pragma unroll
    for (int s = 0; s < 4; ++s) {
        short8 a = *(const short8*)&Abase[s * 32];
        short8 w0 = *(const short8*)&Wg[s * 32];
        short8 w1 = *(const short8*)&Wg[16 * FDIM + s * 32];
        c0 = __builtin_amdgcn_mfma_f32_16x16x32_bf16(w0, a, c0, 0, 0, 0);
        c1 = __builtin_amdgcn_mfma_f32_16x16x32_bf16(w1, a, c1, 0, 0, 0);
    }
    const int r = base + m16;
    if (r < N) {
        ushort4 o;
        o.x = f2bf(c0[0]); o.y = f2bf(c0[1]); o.z = f2bf(c0[2]); o.w = f2bf(c0[3]);
        *(ushort4*)&out[(size_t)r * FDIM + wave * 32 + quad * 4] = o;
        o.x = f2bf(c1[0]); o.y = f2bf(c1[1]); o.z = f2bf(c1[2]); o.w = f2bf(c1[3]);
        *(ushort4*)&out[(size_t)r * FDIM + wave * 32 + 16 + quad * 4] = o;
    }
}

// ---------------------------------------------------------------------------
// 5) layer-2 aggregation + pool (bf16 in, fp32 accum, relu). Same fence-
//    pinned branch-free 8-deep gather as agg_gemm2. Per-block pool partial
//    via plain LDS writes + tree reduce + one coalesced 512B store (tag g0);
//    boundary blocks (~63/12500) use direct atomics (tag -1).
template <bool POOL>
__global__ __launch_bounds__(256) void aggregate(const unsigned short* __restrict__ xw,
                                                 const float* __restrict__ dinv,
                                                 const int* __restrict__ start,
                                                 const int* __restrict__ cnt,
                                                 const int2* __restrict__ edata,
                                                 const float* __restrict__ bvec,
                                                 unsigned short* __restrict__ out,
                                                 const int* __restrict__ batch,
                                                 float* __restrict__ pool_part,
                                                 int* __restrict__ ptag,
                                                 float* __restrict__ pooled, int N) {
    const int base = blockIdx.x * 16;
    const int node = base + (threadIdx.x >> 4);
    const int l8 = threadIdx.x & 15;  // 8-col group
    const bool active = node < N;
    if (!POOL && !active) return;
    const int nidx = active ? node : (N - 1);

    const int j = start[nidx];
    const int c = active ? cnt[nidx] : 0;
    float dv = dinv[nidx];
    float4 b0 = ((const float4*)bvec)[l8 * 2];
    float4 b1 = ((const float4*)bvec)[l8 * 2 + 1];
    short8 sv = *(const short8*)&xw[(size_t)nidx * FDIM + l8 * 8];

    const int jb = (c > 0) ? j : 0;
    const int cm = (c > 0) ? c - 1 : 0;

    int2 e[8];
#pragma unroll
    for (int k = 0; k < 8; ++k) e[k] = edata[jb + min(k, cm)];
    asm volatile("" ::: "memory");

    float d2 = dv * dv;
    float acc[8] = {b0.x, b0.y, b0.z, b0.w, b1.x, b1.y, b1.z, b1.w};
    bf8_fma(sv, d2, acc);

    short8 u[8];
#pragma unroll
    for (int k = 0; k < 8; ++k)
        u[k] = *(const short8*)&xw[(size_t)e[k].x * FDIM + l8 * 8];
    asm volatile("" ::: "memory");

#pragma unroll
    for (int k = 0; k < 8; ++k) {
        float ck = (k < c) ? __int_as_float(e[k].y) : 0.f;
        bf8_fma(u[k], ck, acc);
    }

    for (int k = 8; k < c; ++k) {  // rare: deg > 8
        int2 ed = edata[j + k];
        short8 uu = *(const short8*)&xw[(size_t)ed.x * FDIM + l8 * 8];
        bf8_fma(uu, __int_as_float(ed.y), acc);
    }

    if constexpr (!POOL) {
        short8 o;
#pragma unroll
        for (int k = 0; k < 8; ++k)
            ((unsigned short*)&o)[k] = f2bf(fmaxf(acc[k], 0.f));
        *(short8*)&out[(size_t)node * FDIM + l8 * 8] = o;
    } else {
        float r[8];
#pragma unroll
        for (int k = 0; k < 8; ++k) r[k] = active ? fmaxf(acc[k], 0.f) : 0.f;
        int g0 = batch[base];
        int g1 = batch[min(base + 15, N - 1)];
        if (g0 == g1) {  // block-uniform branch — safe around __syncthreads
            __shared__ float red[16][FDIM];  // 8 KB; plain writes, no LDS atomics
            float* dst = &red[threadIdx.x >> 4][l8 * 8];
            *(float4*)dst = make_float4(r[0], r[1], r[2], r[3]);
            *(float4*)(dst + 4) = make_float4(r[4], r[5], r[6], r[7]);
            __syncthreads();
            if (threadIdx.x < FDIM) {
                float s = 0.f;
#pragma unroll
                for (int i = 0; i < 16; ++i) s += red[i][threadIdx.x];
                pool_part[(size_t)blockIdx.x * FDIM + threadIdx.x] = s;
                if (threadIdx.x == 0) ptag[blockIdx.x] = g0;
            }
        } else {  // rare boundary block: direct atomics, slot skipped
            if (threadIdx.x == 0) ptag[blockIdx.x] = -1;
            if (active) {
                int g = batch[node];
#pragma unroll
                for (int k = 0; k < 8; ++k)
                    unsafeAtomicAdd(&pooled[g * FDIM + l8 * 8 + k], r[k]);
            }
        }
    }
}

// ---------------------------------------------------------------------------
// 6) reduce tagged per-block pool partials into d_out (tags monotone).
__global__ __launch_bounds__(128) void pool_reduce(const float* __restrict__ pool_part,
                                                   const int* __restrict__ ptag,
                                                   int nslots, float* __restrict__ out) {
    int per = (nslots + gridDim.x - 1) / gridDim.x;
    int s0 = blockIdx.x * per;
    int s1 = min(s0 + per, nslots);
    int t = threadIdx.x;
    float acc = 0.f;
    int cur = -1;
    for (int s = s0; s < s1; ++s) {
        int g = ptag[s];  // broadcast scalar load
        if (g < 0) continue;
        if (g != cur) {
            if (cur >= 0) unsafeAtomicAdd(&out[cur * FDIM + t], acc);
            acc = 0.f;
            cur = g;
        }
        acc += pool_part[(size_t)s * FDIM + t];
    }
    if (cur >= 0) unsafeAtomicAdd(&out[cur * FDIM + t], acc);
}

// ---------------------------------------------------------------------------
extern "C" void kernel_launch(void* const* d_in, const int* in_sizes, int n_in,
                              void* d_out, int out_size, void* d_ws, size_t ws_size,
                              hipStream_t stream) {
    const float* x = (const float*)d_in[0];
    const int* ei = (const int*)d_in[1];
    const int* batch = (const int*)d_in[2];
    const float* W1 = (const float*)d_in[4];
    const float* b1 = (const float*)d_in[5];
    const float* W2 = (const float*)d_in[6];
    const float* b2 = (const float*)d_in[7];

    const int N = in_sizes[2];
    const int E = in_sizes[1] / 2;
    const int* srcp = ei;
    const int* dstp = ei + E;

    const size_t NF = (size_t)N * FDIM;
    const int aggGrid = (N + 15) / 16;
    unsigned short* bufA = (unsigned short*)d_ws;  // N*128 bf16 (xw)
    unsigned short* bufB = bufA + NF;              // N*128 bf16 (x_bf16, then h1@W2)
    int* cnt = (int*)(bufB + NF);                  // N      <- memset from here
    int* counter = cnt + N;                        // 4
    float* bias0 = (float*)(counter + 4);          // 128    <- memset to here
    float* dinv = bias0 + FDIM;                    // N
    int* start = (int*)(dinv + N);                 // N
    int* wcur = start + N;                         // N
    unsigned short* WT1 = (unsigned short*)(wcur + N);  // 128*128 bf16
    unsigned short* WT2 = WT1 + FDIM * FDIM;            // 128*128 bf16
    int2* edata = (int2*)(WT2 + FDIM * FDIM);      // E x {src, coef}
    float* pool_part = (float*)(edata + E);        // aggGrid*128 f32
    int* ptag = (int*)(pool_part + (size_t)aggGrid * FDIM);  // aggGrid
    float* partials = (float*)edata;               // aliased; dead before gemm1_fill
    const int STAT_BLOCKS = 512;

    hipMemsetAsync(cnt, 0, ((size_t)N + 4 + FDIM) * sizeof(int), stream);
    hipMemsetAsync(d_out, 0, (size_t)out_size * sizeof(float), stream);

    const int degBlocks = (E + 255) / 256;
    const int offsBlocks = (N + 255) / 256;
    const int gemmGrid = (N + 63) / 64;

    // pre_combo also emits bf16 cast of x into bufB (dead until agg_gemm2
    // overwrites it) — gemm1_fill then reads 51 MB instead of 102 MB.
    pre_combo<<<STAT_BLOCKS + degBlocks, 256, 0, stream>>>(x, N, partials, STAT_BLOCKS,
                                                           dstp, E, cnt, bufB);
    mid_combo<<<offsBlocks + 16, 256, 0, stream>>>(cnt, N, start, wcur, counter, dinv,
                                                   partials, STAT_BLOCKS, offsBlocks,
                                                   W1, W2, WT1, WT2, bias0);

    // ---- layer 1 GEMM (reads x_bf16) + edge bucketing overlapped
    gemm1_fill<<<gemmGrid + degBlocks, 256, 0, stream>>>(bufB, WT1, bias0, bufA, N,
                                                         gemmGrid, srcp, dstp, dinv,
                                                         wcur, edata, E);

    // ---- layer-1 aggregate + layer-2 GEMM fused (h1 never hits HBM)
    agg_gemm2<<<aggGrid, 256, 0, stream>>>(bufA, dinv, start, cnt, edata, b1, WT2,
                                           bufB, N);

    // ---- layer-2 aggregate + pool fused (h2 never materialized)
    aggregate<true><<<aggGrid, 256, 0, stream>>>(bufB, dinv, start, cnt, edata, b2,
                                                 nullptr, batch, pool_part, ptag,
                                                 (float*)d_out, N);
    pool_reduce<<<256, 128, 0, stream>>>(pool_part, ptag, aggGrid, (float*)d_out);
}

// Round 7
// 411.247 us; speedup vs baseline: 1.0039x; 1.0039x over previous
//
#include <hip/hip_runtime.h>

#define FDIM 128  // feature dim == hidden dim

typedef __attribute__((ext_vector_type(8))) short short8;   // 8 bf16 (4 VGPRs)
typedef __attribute__((ext_vector_type(4))) float f32x4;    // MFMA accumulator

__device__ inline unsigned short f2bf(float f) {  // round-to-nearest-even
    unsigned int u = __float_as_uint(f);
    unsigned int r = u + 0x7FFFu + ((u >> 16) & 1u);
    return (unsigned short)(r >> 16);
}
__device__ inline float bf2f(unsigned short b) {
    return __uint_as_float((unsigned int)b << 16);
}
__device__ inline void bf8_fma(short8 v, float c, float* acc) {
#pragma unroll
    for (int k = 0; k < 8; ++k)
        acc[k] = fmaf(bf2f(((const unsigned short*)&v)[k]), c, acc[k]);
}

// ---------------------------------------------------------------------------
// 1) heterogeneous pre-pass: blocks [0,statBlocks) = column sum/sumsq partials
//    (BW-bound sweep of x) + bf16 cast of x written to xbf (aliases bufB,
//    dead until agg_gemm2) so gemm1 reads 51 MB instead of 102 MB;
//    blocks >= statBlocks = dst-degree atomics (latency-bound) — merged so
//    the two run concurrently.
__global__ __launch_bounds__(256) void pre_combo(const float* __restrict__ x, int N,
                                                 float* __restrict__ partials, int statBlocks,
                                                 const int* __restrict__ dst, int E,
                                                 int* __restrict__ cnt,
                                                 unsigned short* __restrict__ xbf) {
    if ((int)blockIdx.x >= statBlocks) {
        int e = (blockIdx.x - statBlocks) * 256 + threadIdx.x;
        if (e < E) atomicAdd(&cnt[dst[e]], 1);
        return;
    }
    const int c4 = threadIdx.x & 31;
    const int rg = threadIdx.x >> 5;
    float4 s = make_float4(0.f, 0.f, 0.f, 0.f);
    float4 q = make_float4(0.f, 0.f, 0.f, 0.f);
    for (long r = (long)blockIdx.x * 8 + rg; r < N; r += (long)statBlocks * 8) {
        float4 v = ((const float4*)x)[r * 32 + c4];
        s.x += v.x; s.y += v.y; s.z += v.z; s.w += v.w;
        q.x += v.x * v.x; q.y += v.y * v.y; q.z += v.z * v.z; q.w += v.w * v.w;
        ushort4 p;
        p.x = f2bf(v.x); p.y = f2bf(v.y); p.z = f2bf(v.z); p.w = f2bf(v.w);
        ((ushort4*)xbf)[r * 32 + c4] = p;
    }
    __shared__ float red[8][32][8];
    float* p = red[rg][c4];
    p[0] = s.x; p[1] = s.y; p[2] = s.z; p[3] = s.w;
    p[4] = q.x; p[5] = q.y; p[6] = q.z; p[7] = q.w;
    __syncthreads();
    if (rg == 0) {
#pragma unroll
        for (int g = 1; g < 8; ++g) {
            const float* o = red[g][c4];
#pragma unroll
            for (int j = 0; j < 8; ++j) red[0][c4][j] += o[j];
        }
        const float* r0 = red[0][c4];
        float* out = &partials[(size_t)blockIdx.x * 256];
        ((float4*)out)[c4] = make_float4(r0[0], r0[1], r0[2], r0[3]);
        ((float4*)(out + 128))[c4] = make_float4(r0[4], r0[5], r0[6], r0[7]);
    }
}

// ---------------------------------------------------------------------------
// 2) mid_combo: blocks [0, offsBlocks) = per-node edge-range scan + dinv;
//    blocks offsBlocks..+8 = W1 stats-slice reduce + scaled transpose + bias0;
//    blocks +8..+16 = W2 transpose.
__global__ __launch_bounds__(256) void mid_combo(const int* __restrict__ cnt, int N,
                                                 int* __restrict__ start,
                                                 int* __restrict__ wcur,
                                                 int* __restrict__ counter,
                                                 float* __restrict__ dinv,
                                                 const float* __restrict__ partials,
                                                 int nblk, int offsBlocks,
                                                 const float* __restrict__ W1,
                                                 const float* __restrict__ W2,
                                                 unsigned short* __restrict__ WT1,
                                                 unsigned short* __restrict__ WT2,
                                                 float* __restrict__ bias0) {
    const int tid = threadIdx.x;
    if ((int)blockIdx.x < offsBlocks) {
        __shared__ int sh[256];
        __shared__ int base;
        int i = blockIdx.x * 256 + tid;
        int v = (i < N) ? cnt[i] : 0;
        sh[tid] = v;
        __syncthreads();
        for (int off = 1; off < 256; off <<= 1) {
            int t = (tid >= off) ? sh[tid - off] : 0;
            __syncthreads();
            sh[tid] += t;
            __syncthreads();
        }
        if (tid == 255) base = atomicAdd(counter, sh[255]);
        __syncthreads();
        int excl = base + sh[tid] - v;
        if (i < N) {
            start[i] = excl;
            wcur[i] = excl;
            dinv[i] = rsqrtf((float)v + 1.0f);
        }
        return;
    }
    const int b = blockIdx.x - offsBlocks;  // 0..15
    const int h = tid & 127;
    const int seg = tid >> 7;  // 0,1
    if (b < 8) {
        // reduce this block's 32-col slice: 16 sum cols + 16 sumsq cols
        __shared__ float red[32][32];  // [rowgroup][localcol] 4 KB
        __shared__ float scol[32], mean_sh[16], rstd_sh[16];
        const int rg = tid >> 3;      // 0..31
        const int f = tid & 7;        // 0..7
        const int colbase = (f < 4) ? (b * 16 + f * 4) : (128 + b * 16 + (f - 4) * 4);
        float4 a = make_float4(0.f, 0.f, 0.f, 0.f);
        for (int row = rg; row < nblk; row += 32) {
            float4 v = *(const float4*)&partials[(size_t)row * 256 + colbase];
            a.x += v.x; a.y += v.y; a.z += v.z; a.w += v.w;
        }
        *(float4*)&red[rg][f * 4] = a;
        __syncthreads();
        if (tid < 32) {
            float s = 0.f;
#pragma unroll
            for (int r = 0; r < 32; ++r) s += red[r][tid];
            scol[tid] = s;
        }
        __syncthreads();
        if (tid < 16) {
            float m = scol[tid] / (float)N;
            float var = (scol[16 + tid] - (float)N * m * m) / (float)(N - 1);
            mean_sh[tid] = m;
            rstd_sh[tid] = rsqrtf(var);
        }
        __syncthreads();
        float acc = 0.f;
#pragma unroll
        for (int jj = 0; jj < 8; ++jj) {
            int jl = seg * 8 + jj;
            int j2 = b * 16 + jl;
            float w = W1[j2 * FDIM + h] * rstd_sh[jl];
            WT1[h * FDIM + j2] = f2bf(w);
            acc += mean_sh[jl] * w;
        }
        unsafeAtomicAdd(&bias0[h], -acc);
    } else {
#pragma unroll
        for (int jj = 0; jj < 8; ++jj) {
            int j2 = (b - 8) * 16 + seg * 8 + jj;
            WT2[h * FDIM + j2] = f2bf(W2[j2 * FDIM + h]);
        }
    }
}

// ---------------------------------------------------------------------------
// 3) GEMM1 + edge-bucketing merged. MFMA operands SWAPPED (W-frag as A,
//    x-frag as B) so D comes out transposed: m=h-within-tile (quad*4+reg),
//    n=x-row (lane&15). Epilogue = 8 contiguous short4 stores per lane.
//    W stays in LDS (round-2 lesson: W-frags from global put an L2 hit on
//    every MFMA's critical path — load latency, not occupancy, is binding).
//    A is read pre-cast bf16 (xbf from pre_combo).
__global__ __launch_bounds__(256) void gemm1_fill(const unsigned short* __restrict__ A,
                                                  const unsigned short* __restrict__ WT,
                                                  const float* __restrict__ bias,
                                                  unsigned short* __restrict__ C, int M,
                                                  int gemmBlocks,
                                                  const int* __restrict__ src,
                                                  const int* __restrict__ dst,
                                                  const float* __restrict__ dinv,
                                                  int* __restrict__ wcur,
                                                  int2* __restrict__ edata, int E) {
    const int tid = threadIdx.x;
    if ((int)blockIdx.x >= gemmBlocks) {
        int e = (blockIdx.x - gemmBlocks) * 256 + tid;
        if (e < E) {
            int s = src[e], d = dst[e];
            int pos = atomicAdd(&wcur[d], 1);
            edata[pos] = make_int2(s, __float_as_int(dinv[s] * dinv[d]));
        }
        return;
    }
    constexpr int LDA = 136;
    __shared__ unsigned short Alds[64 * LDA];
    __shared__ unsigned short Wlds[FDIM * LDA];
    const int row0 = blockIdx.x * 64;

    for (int i = tid; i < FDIM * 16; i += 256) {
        int r = i >> 4, g = i & 15;
        *(int4*)&Wlds[r * LDA + g * 8] = *(const int4*)&WT[r * FDIM + g * 8];
    }
    for (int i = tid; i < 64 * 16; i += 256) {
        int r = i >> 4, g = i & 15;
        int row = row0 + r;
        int4 v = make_int4(0, 0, 0, 0);
        if (row < M) v = *(const int4*)&A[(size_t)row * FDIM + g * 8];
        *(int4*)&Alds[r * LDA + g * 8] = v;
    }
    __syncthreads();

    const int lane = tid & 63;
    const int wave = tid >> 6;
    const int m16 = lane & 15;
    const int quad = lane >> 4;

    f32x4 acc[8];
#pragma unroll
    for (int t = 0; t < 8; ++t) acc[t] = (f32x4){0.f, 0.f, 0.f, 0.f};

    const unsigned short* Abase = &Alds[(wave * 16 + m16) * LDA + quad * 8];
    const unsigned short* Wbase = &Wlds[m16 * LDA + quad * 8];
#pragma unroll
    for (int s = 0; s < 4; ++s) {
        short8 a = *(const short8*)&Abase[s * 32];
#pragma unroll
        for (int t = 0; t < 8; ++t) {
            short8 b = *(const short8*)&Wbase[t * 16 * LDA + s * 32];
            // swapped: W-frag is the A operand -> D[m=h][n=x-row]
            acc[t] = __builtin_amdgcn_mfma_f32_16x16x32_bf16(b, a, acc[t], 0, 0, 0);
        }
    }

    // epilogue: lane's x-row = m16 (fixed); per t a contiguous short4 at
    // col t*16 + quad*4.
    const int r = row0 + wave * 16 + m16;
    if (r < M) {
#pragma unroll
        for (int t = 0; t < 8; ++t) {
            ushort4 o;
            o.x = f2bf(acc[t][0] + bias[t * 16 + quad * 4 + 0]);
            o.y = f2bf(acc[t][1] + bias[t * 16 + quad * 4 + 1]);
            o.z = f2bf(acc[t][2] + bias[t * 16 + quad * 4 + 2]);
            o.w = f2bf(acc[t][3] + bias[t * 16 + quad * 4 + 3]);
            *(ushort4*)&C[(size_t)r * FDIM + t * 16 + quad * 4] = o;
        }
    }
}

// ---------------------------------------------------------------------------
// 4) layer-1 aggregation FUSED with the layer-2 GEMM. Gather = branch-free
//    8-deep batch pinned with sched_barrier(0) (round-6 lesson / guide rule
//    #18: a plain asm "memory" clobber only orders MEMORY ops — the FMAs and
//    bf2f shifts are register-only VALU and were hoisted INTO the load batch,
//    re-serializing it; VGPR stayed 40). sched_barrier(0) blocks ALL movement
//    across it: the 8 row loads must issue before the first FMA -> their
//    latencies overlap (one vmcnt drain per batch instead of ~deg).
//    Loads unconditional with clamped indices (dups -> same addr -> L1 hit);
//    correctness via zeroed coefficient (fma(x,0,acc) bitwise identity).
__global__ __launch_bounds__(256) void agg_gemm2(const unsigned short* __restrict__ xw,
                                                 const float* __restrict__ dinv,
                                                 const int* __restrict__ start,
                                                 const int* __restrict__ cnt,
                                                 const int2* __restrict__ edata,
                                                 const float* __restrict__ bvec,
                                                 const unsigned short* __restrict__ WT2,
                                                 unsigned short* __restrict__ out,
                                                 int N) {
    const int base = blockIdx.x * 16;
    const int node = base + (threadIdx.x >> 4);
    const int l8 = threadIdx.x & 15;  // 8-col group
    const bool active = node < N;     // NO early return: __syncthreads below
    const int nidx = active ? node : (N - 1);

    // exposure 1: all node-scalar + self-row loads issued together
    const int j = start[nidx];
    const int c = active ? cnt[nidx] : 0;
    float dv = dinv[nidx];
    float4 b0 = ((const float4*)bvec)[l8 * 2];
    float4 b1v = ((const float4*)bvec)[l8 * 2 + 1];
    short8 sv = *(const short8*)&xw[(size_t)nidx * FDIM + l8 * 8];

    const int jb = (c > 0) ? j : 0;       // safe base when deg==0
    const int cm = (c > 0) ? c - 1 : 0;   // clamp offset

    // exposure 2: edata batch (contiguous <=64B region), pinned
    int2 e[8];
#pragma unroll
    for (int k = 0; k < 8; ++k) e[k] = edata[jb + min(k, cm)];
    __builtin_amdgcn_sched_barrier(0);  // hard pin: nothing crosses

    float d2 = dv * dv;
    float acc[8] = {b0.x, b0.y, b0.z, b0.w, b1v.x, b1v.y, b1v.z, b1v.w};
    bf8_fma(sv, d2, acc);

    // exposure 3: row batch, pinned — all 8 loads issue before any FMA
    short8 u[8];
#pragma unroll
    for (int k = 0; k < 8; ++k)
        u[k] = *(const short8*)&xw[(size_t)e[k].x * FDIM + l8 * 8];
    __builtin_amdgcn_sched_barrier(0);  // hard pin: FMAs cannot hoist in

#pragma unroll
    for (int k = 0; k < 8; ++k) {
        float ck = (k < c) ? __int_as_float(e[k].y) : 0.f;
        bf8_fma(u[k], ck, acc);
    }

    for (int k = 8; k < c; ++k) {  // rare: deg > 8
        int2 ed = edata[j + k];
        short8 uu = *(const short8*)&xw[(size_t)ed.x * FDIM + l8 * 8];
        bf8_fma(uu, __int_as_float(ed.y), acc);
    }

    // relu + stage the 16x128 h1 tile (bf16) for the MFMA
    constexpr int LDH = 136;
    __shared__ unsigned short hlds[16 * LDH];  // 4.25 KiB
    {
        ushort4 o0, o1;
        if (active) {
            o0.x = f2bf(fmaxf(acc[0], 0.f)); o0.y = f2bf(fmaxf(acc[1], 0.f));
            o0.z = f2bf(fmaxf(acc[2], 0.f)); o0.w = f2bf(fmaxf(acc[3], 0.f));
            o1.x = f2bf(fmaxf(acc[4], 0.f)); o1.y = f2bf(fmaxf(acc[5], 0.f));
            o1.z = f2bf(fmaxf(acc[6], 0.f)); o1.w = f2bf(fmaxf(acc[7], 0.f));
        } else {
            o0.x = 0; o0.y = 0; o0.z = 0; o0.w = 0;
            o1.x = 0; o1.y = 0; o1.z = 0; o1.w = 0;
        }
        unsigned short* hp = &hlds[(threadIdx.x >> 4) * LDH + l8 * 8];
        *(ushort4*)hp = o0;
        *(ushort4*)(hp + 4) = o1;
    }
    __syncthreads();

    // swapped-operand MFMA: D[m=h][n=node]; wave w owns h-cols [w*32, w*32+32)
    const int lane = threadIdx.x & 63;
    const int wave = threadIdx.x >> 6;
    const int m16 = lane & 15;
    const int quad = lane >> 4;
    f32x4 c0 = (f32x4){0.f, 0.f, 0.f, 0.f};
    f32x4 c1 = (f32x4){0.f, 0.f, 0.f, 0.f};
    const unsigned short* Abase = &hlds[m16 * LDH + quad * 8];
    const unsigned short* Wg = &WT2[(size_t)(wave * 32 + m16) * FDIM + quad * 8];
#pragma unroll
    for (int s = 0; s < 4; ++s) {
        short8 a = *(const short8*)&Abase[s * 32];
        short8 w0 = *(const short8*)&Wg[s * 32];
        short8 w1 = *(const short8*)&Wg[16 * FDIM + s * 32];
        c0 = __builtin_amdgcn_mfma_f32_16x16x32_bf16(w0, a, c0, 0, 0, 0);
        c1 = __builtin_amdgcn_mfma_f32_16x16x32_bf16(w1, a, c1, 0, 0, 0);
    }
    const int r = base + m16;
    if (r < N) {
        ushort4 o;
        o.x = f2bf(c0[0]); o.y = f2bf(c0[1]); o.z = f2bf(c0[2]); o.w = f2bf(c0[3]);
        *(ushort4*)&out[(size_t)r * FDIM + wave * 32 + quad * 4] = o;
        o.x = f2bf(c1[0]); o.y = f2bf(c1[1]); o.z = f2bf(c1[2]); o.w = f2bf(c1[3]);
        *(ushort4*)&out[(size_t)r * FDIM + wave * 32 + 16 + quad * 4] = o;
    }
}

// ---------------------------------------------------------------------------
// 5) layer-2 aggregation + pool (bf16 in, fp32 accum, relu). Same sched-
//    barrier-pinned branch-free 8-deep gather as agg_gemm2. Per-block pool
//    partial via plain LDS writes + tree reduce + one coalesced 512B store
//    (tag g0); boundary blocks (~63/12500) use direct atomics (tag -1).
template <bool POOL>
__global__ __launch_bounds__(256) void aggregate(const unsigned short* __restrict__ xw,
                                                 const float* __restrict__ dinv,
                                                 const int* __restrict__ start,
                                                 const int* __restrict__ cnt,
                                                 const int2* __restrict__ edata,
                                                 const float* __restrict__ bvec,
                                                 unsigned short* __restrict__ out,
                                                 const int* __restrict__ batch,
                                                 float* __restrict__ pool_part,
                                                 int* __restrict__ ptag,
                                                 float* __restrict__ pooled, int N) {
    const int base = blockIdx.x * 16;
    const int node = base + (threadIdx.x >> 4);
    const int l8 = threadIdx.x & 15;  // 8-col group
    const bool active = node < N;
    if (!POOL && !active) return;
    const int nidx = active ? node : (N - 1);

    const int j = start[nidx];
    const int c = active ? cnt[nidx] : 0;
    float dv = dinv[nidx];
    float4 b0 = ((const float4*)bvec)[l8 * 2];
    float4 b1 = ((const float4*)bvec)[l8 * 2 + 1];
    short8 sv = *(const short8*)&xw[(size_t)nidx * FDIM + l8 * 8];

    const int jb = (c > 0) ? j : 0;
    const int cm = (c > 0) ? c - 1 : 0;

    int2 e[8];
#pragma unroll
    for (int k = 0; k < 8; ++k) e[k] = edata[jb + min(k, cm)];
    __builtin_amdgcn_sched_barrier(0);

    float d2 = dv * dv;
    float acc[8] = {b0.x, b0.y, b0.z, b0.w, b1.x, b1.y, b1.z, b1.w};
    bf8_fma(sv, d2, acc);

    short8 u[8];
#pragma unroll
    for (int k = 0; k < 8; ++k)
        u[k] = *(const short8*)&xw[(size_t)e[k].x * FDIM + l8 * 8];
    __builtin_amdgcn_sched_barrier(0);

#pragma unroll
    for (int k = 0; k < 8; ++k) {
        float ck = (k < c) ? __int_as_float(e[k].y) : 0.f;
        bf8_fma(u[k], ck, acc);
    }

    for (int k = 8; k < c; ++k) {  // rare: deg > 8
        int2 ed = edata[j + k];
        short8 uu = *(const short8*)&xw[(size_t)ed.x * FDIM + l8 * 8];
        bf8_fma(uu, __int_as_float(ed.y), acc);
    }

    if constexpr (!POOL) {
        short8 o;
#pragma unroll
        for (int k = 0; k < 8; ++k)
            ((unsigned short*)&o)[k] = f2bf(fmaxf(acc[k], 0.f));
        *(short8*)&out[(size_t)node * FDIM + l8 * 8] = o;
    } else {
        float r[8];
#pragma unroll
        for (int k = 0; k < 8; ++k) r[k] = active ? fmaxf(acc[k], 0.f) : 0.f;
        int g0 = batch[base];
        int g1 = batch[min(base + 15, N - 1)];
        if (g0 == g1) {  // block-uniform branch — safe around __syncthreads
            __shared__ float red[16][FDIM];  // 8 KB; plain writes, no LDS atomics
            float* dst = &red[threadIdx.x >> 4][l8 * 8];
            *(float4*)dst = make_float4(r[0], r[1], r[2], r[3]);
            *(float4*)(dst + 4) = make_float4(r[4], r[5], r[6], r[7]);
            __syncthreads();
            if (threadIdx.x < FDIM) {
                float s = 0.f;
#pragma unroll
                for (int i = 0; i < 16; ++i) s += red[i][threadIdx.x];
                pool_part[(size_t)blockIdx.x * FDIM + threadIdx.x] = s;
                if (threadIdx.x == 0) ptag[blockIdx.x] = g0;
            }
        } else {  // rare boundary block: direct atomics, slot skipped
            if (threadIdx.x == 0) ptag[blockIdx.x] = -1;
            if (active) {
                int g = batch[node];
#pragma unroll
                for (int k = 0; k < 8; ++k)
                    unsafeAtomicAdd(&pooled[g * FDIM + l8 * 8 + k], r[k]);
            }
        }
    }
}

// ---------------------------------------------------------------------------
// 6) reduce tagged per-block pool partials into d_out (tags monotone).
__global__ __launch_bounds__(128) void pool_reduce(const float* __restrict__ pool_part,
                                                   const int* __restrict__ ptag,
                                                   int nslots, float* __restrict__ out) {
    int per = (nslots + gridDim.x - 1) / gridDim.x;
    int s0 = blockIdx.x * per;
    int s1 = min(s0 + per, nslots);
    int t = threadIdx.x;
    float acc = 0.f;
    int cur = -1;
    for (int s = s0; s < s1; ++s) {
        int g = ptag[s];  // broadcast scalar load
        if (g < 0) continue;
        if (g != cur) {
            if (cur >= 0) unsafeAtomicAdd(&out[cur * FDIM + t], acc);
            acc = 0.f;
            cur = g;
        }
        acc += pool_part[(size_t)s * FDIM + t];
    }
    if (cur >= 0) unsafeAtomicAdd(&out[cur * FDIM + t], acc);
}

// ---------------------------------------------------------------------------
extern "C" void kernel_launch(void* const* d_in, const int* in_sizes, int n_in,
                              void* d_out, int out_size, void* d_ws, size_t ws_size,
                              hipStream_t stream) {
    const float* x = (const float*)d_in[0];
    const int* ei = (const int*)d_in[1];
    const int* batch = (const int*)d_in[2];
    const float* W1 = (const float*)d_in[4];
    const float* b1 = (const float*)d_in[5];
    const float* W2 = (const float*)d_in[6];
    const float* b2 = (const float*)d_in[7];

    const int N = in_sizes[2];
    const int E = in_sizes[1] / 2;
    const int* srcp = ei;
    const int* dstp = ei + E;

    const size_t NF = (size_t)N * FDIM;
    const int aggGrid = (N + 15) / 16;
    unsigned short* bufA = (unsigned short*)d_ws;  // N*128 bf16 (xw)
    unsigned short* bufB = bufA + NF;              // N*128 bf16 (x_bf16, then h1@W2)
    int* cnt = (int*)(bufB + NF);                  // N      <- memset from here
    int* counter = cnt + N;                        // 4
    float* bias0 = (float*)(counter + 4);          // 128    <- memset to here
    float* dinv = bias0 + FDIM;                    // N
    int* start = (int*)(dinv + N);                 // N
    int* wcur = start + N;                         // N
    unsigned short* WT1 = (unsigned short*)(wcur + N);  // 128*128 bf16
    unsigned short* WT2 = WT1 + FDIM * FDIM;            // 128*128 bf16
    int2* edata = (int2*)(WT2 + FDIM * FDIM);      // E x {src, coef}
    float* pool_part = (float*)(edata + E);        // aggGrid*128 f32
    int* ptag = (int*)(pool_part + (size_t)aggGrid * FDIM);  // aggGrid
    float* partials = (float*)edata;               // aliased; dead before gemm1_fill
    const int STAT_BLOCKS = 512;

    hipMemsetAsync(cnt, 0, ((size_t)N + 4 + FDIM) * sizeof(int), stream);
    hipMemsetAsync(d_out, 0, (size_t)out_size * sizeof(float), stream);

    const int degBlocks = (E + 255) / 256;
    const int offsBlocks = (N + 255) / 256;
    const int gemmGrid = (N + 63) / 64;

    // pre_combo also emits bf16 cast of x into bufB (dead until agg_gemm2
    // overwrites it) — gemm1_fill then reads 51 MB instead of 102 MB.
    pre_combo<<<STAT_BLOCKS + degBlocks, 256, 0, stream>>>(x, N, partials, STAT_BLOCKS,
                                                           dstp, E, cnt, bufB);
    mid_combo<<<offsBlocks + 16, 256, 0, stream>>>(cnt, N, start, wcur, counter, dinv,
                                                   partials, STAT_BLOCKS, offsBlocks,
                                                   W1, W2, WT1, WT2, bias0);

    // ---- layer 1 GEMM (reads x_bf16) + edge bucketing overlapped
    gemm1_fill<<<gemmGrid + degBlocks, 256, 0, stream>>>(bufB, WT1, bias0, bufA, N,
                                                         gemmGrid, srcp, dstp, dinv,
                                                         wcur, edata, E);

    // ---- layer-1 aggregate + layer-2 GEMM fused (h1 never hits HBM)
    agg_gemm2<<<aggGrid, 256, 0, stream>>>(bufA, dinv, start, cnt, edata, b1, WT2,
                                           bufB, N);

    // ---- layer-2 aggregate + pool fused (h2 never materialized)
    aggregate<true><<<aggGrid, 256, 0, stream>>>(bufB, dinv, start, cnt, edata, b2,
                                                 nullptr, batch, pool_part, ptag,
                                                 (float*)d_out, N);
    pool_reduce<<<256, 128, 0, stream>>>(pool_part, ptag, aggGrid, (float*)d_out);
}

// Round 8
// 392.296 us; speedup vs baseline: 1.0524x; 1.0483x over previous
//
#include <hip/hip_runtime.h>

#define FDIM 128  // feature dim == hidden dim

typedef __attribute__((ext_vector_type(8))) short short8;   // 8 bf16 (4 VGPRs)
typedef __attribute__((ext_vector_type(4))) float f32x4;    // MFMA accumulator

__device__ inline unsigned short f2bf(float f) {  // round-to-nearest-even
    unsigned int u = __float_as_uint(f);
    unsigned int r = u + 0x7FFFu + ((u >> 16) & 1u);
    return (unsigned short)(r >> 16);
}
__device__ inline float bf2f(unsigned short b) {
    return __uint_as_float((unsigned int)b << 16);
}
__device__ inline void bf8_fma(short8 v, float c, float* acc) {
#pragma unroll
    for (int k = 0; k < 8; ++k)
        acc[k] = fmaf(bf2f(((const unsigned short*)&v)[k]), c, acc[k]);
}

// ---------------------------------------------------------------------------
// 1) heterogeneous pre-pass: blocks [0,statBlocks) = column sum/sumsq partials
//    (BW-bound sweep of x) + bf16 cast of x written to xbf (aliases bufB,
//    dead until agg_gemm2) so gemm1 reads 51 MB instead of 102 MB;
//    blocks >= statBlocks = dst-degree atomics (latency-bound) — merged so
//    the two run concurrently.
__global__ __launch_bounds__(256) void pre_combo(const float* __restrict__ x, int N,
                                                 float* __restrict__ partials, int statBlocks,
                                                 const int* __restrict__ dst, int E,
                                                 int* __restrict__ cnt,
                                                 unsigned short* __restrict__ xbf) {
    if ((int)blockIdx.x >= statBlocks) {
        int e = (blockIdx.x - statBlocks) * 256 + threadIdx.x;
        if (e < E) atomicAdd(&cnt[dst[e]], 1);
        return;
    }
    const int c4 = threadIdx.x & 31;
    const int rg = threadIdx.x >> 5;
    float4 s = make_float4(0.f, 0.f, 0.f, 0.f);
    float4 q = make_float4(0.f, 0.f, 0.f, 0.f);
    for (long r = (long)blockIdx.x * 8 + rg; r < N; r += (long)statBlocks * 8) {
        float4 v = ((const float4*)x)[r * 32 + c4];
        s.x += v.x; s.y += v.y; s.z += v.z; s.w += v.w;
        q.x += v.x * v.x; q.y += v.y * v.y; q.z += v.z * v.z; q.w += v.w * v.w;
        ushort4 p;
        p.x = f2bf(v.x); p.y = f2bf(v.y); p.z = f2bf(v.z); p.w = f2bf(v.w);
        ((ushort4*)xbf)[r * 32 + c4] = p;
    }
    __shared__ float red[8][32][8];
    float* p = red[rg][c4];
    p[0] = s.x; p[1] = s.y; p[2] = s.z; p[3] = s.w;
    p[4] = q.x; p[5] = q.y; p[6] = q.z; p[7] = q.w;
    __syncthreads();
    if (rg == 0) {
#pragma unroll
        for (int g = 1; g < 8; ++g) {
            const float* o = red[g][c4];
#pragma unroll
            for (int j = 0; j < 8; ++j) red[0][c4][j] += o[j];
        }
        const float* r0 = red[0][c4];
        float* out = &partials[(size_t)blockIdx.x * 256];
        ((float4*)out)[c4] = make_float4(r0[0], r0[1], r0[2], r0[3]);
        ((float4*)(out + 128))[c4] = make_float4(r0[4], r0[5], r0[6], r0[7]);
    }
}

// ---------------------------------------------------------------------------
// 2) mid_combo: blocks [0, offsBlocks) = per-node edge-range scan + dinv;
//    blocks offsBlocks..+8 = W1 stats-slice reduce + scaled transpose + bias0;
//    blocks +8..+16 = W2 transpose.
__global__ __launch_bounds__(256) void mid_combo(const int* __restrict__ cnt, int N,
                                                 int* __restrict__ start,
                                                 int* __restrict__ wcur,
                                                 int* __restrict__ counter,
                                                 float* __restrict__ dinv,
                                                 const float* __restrict__ partials,
                                                 int nblk, int offsBlocks,
                                                 const float* __restrict__ W1,
                                                 const float* __restrict__ W2,
                                                 unsigned short* __restrict__ WT1,
                                                 unsigned short* __restrict__ WT2,
                                                 float* __restrict__ bias0) {
    const int tid = threadIdx.x;
    if ((int)blockIdx.x < offsBlocks) {
        __shared__ int sh[256];
        __shared__ int base;
        int i = blockIdx.x * 256 + tid;
        int v = (i < N) ? cnt[i] : 0;
        sh[tid] = v;
        __syncthreads();
        for (int off = 1; off < 256; off <<= 1) {
            int t = (tid >= off) ? sh[tid - off] : 0;
            __syncthreads();
            sh[tid] += t;
            __syncthreads();
        }
        if (tid == 255) base = atomicAdd(counter, sh[255]);
        __syncthreads();
        int excl = base + sh[tid] - v;
        if (i < N) {
            start[i] = excl;
            wcur[i] = excl;
            dinv[i] = rsqrtf((float)v + 1.0f);
        }
        return;
    }
    const int b = blockIdx.x - offsBlocks;  // 0..15
    const int h = tid & 127;
    const int seg = tid >> 7;  // 0,1
    if (b < 8) {
        // reduce this block's 32-col slice: 16 sum cols + 16 sumsq cols
        __shared__ float red[32][32];  // [rowgroup][localcol] 4 KB
        __shared__ float scol[32], mean_sh[16], rstd_sh[16];
        const int rg = tid >> 3;      // 0..31
        const int f = tid & 7;        // 0..7
        const int colbase = (f < 4) ? (b * 16 + f * 4) : (128 + b * 16 + (f - 4) * 4);
        float4 a = make_float4(0.f, 0.f, 0.f, 0.f);
        for (int row = rg; row < nblk; row += 32) {
            float4 v = *(const float4*)&partials[(size_t)row * 256 + colbase];
            a.x += v.x; a.y += v.y; a.z += v.z; a.w += v.w;
        }
        *(float4*)&red[rg][f * 4] = a;
        __syncthreads();
        if (tid < 32) {
            float s = 0.f;
#pragma unroll
            for (int r = 0; r < 32; ++r) s += red[r][tid];
            scol[tid] = s;
        }
        __syncthreads();
        if (tid < 16) {
            float m = scol[tid] / (float)N;
            float var = (scol[16 + tid] - (float)N * m * m) / (float)(N - 1);
            mean_sh[tid] = m;
            rstd_sh[tid] = rsqrtf(var);
        }
        __syncthreads();
        float acc = 0.f;
#pragma unroll
        for (int jj = 0; jj < 8; ++jj) {
            int jl = seg * 8 + jj;
            int j2 = b * 16 + jl;
            float w = W1[j2 * FDIM + h] * rstd_sh[jl];
            WT1[h * FDIM + j2] = f2bf(w);
            acc += mean_sh[jl] * w;
        }
        unsafeAtomicAdd(&bias0[h], -acc);
    } else {
#pragma unroll
        for (int jj = 0; jj < 8; ++jj) {
            int j2 = (b - 8) * 16 + seg * 8 + jj;
            WT2[h * FDIM + j2] = f2bf(W2[j2 * FDIM + h]);
        }
    }
}

// ---------------------------------------------------------------------------
// 3) GEMM1 + edge-bucketing merged. MFMA operands SWAPPED (W-frag as A,
//    x-frag as B) so D comes out transposed: m=h-within-tile (quad*4+reg),
//    n=x-row (lane&15). W stays in LDS (round-2 lesson). A read pre-cast
//    bf16 (xbf from pre_combo).
__global__ __launch_bounds__(256) void gemm1_fill(const unsigned short* __restrict__ A,
                                                  const unsigned short* __restrict__ WT,
                                                  const float* __restrict__ bias,
                                                  unsigned short* __restrict__ C, int M,
                                                  int gemmBlocks,
                                                  const int* __restrict__ src,
                                                  const int* __restrict__ dst,
                                                  const float* __restrict__ dinv,
                                                  int* __restrict__ wcur,
                                                  int2* __restrict__ edata, int E) {
    const int tid = threadIdx.x;
    if ((int)blockIdx.x >= gemmBlocks) {
        int e = (blockIdx.x - gemmBlocks) * 256 + tid;
        if (e < E) {
            int s = src[e], d = dst[e];
            int pos = atomicAdd(&wcur[d], 1);
            edata[pos] = make_int2(s, __float_as_int(dinv[s] * dinv[d]));
        }
        return;
    }
    constexpr int LDA = 136;
    __shared__ unsigned short Alds[64 * LDA];
    __shared__ unsigned short Wlds[FDIM * LDA];
    const int row0 = blockIdx.x * 64;

    for (int i = tid; i < FDIM * 16; i += 256) {
        int r = i >> 4, g = i & 15;
        *(int4*)&Wlds[r * LDA + g * 8] = *(const int4*)&WT[r * FDIM + g * 8];
    }
    for (int i = tid; i < 64 * 16; i += 256) {
        int r = i >> 4, g = i & 15;
        int row = row0 + r;
        int4 v = make_int4(0, 0, 0, 0);
        if (row < M) v = *(const int4*)&A[(size_t)row * FDIM + g * 8];
        *(int4*)&Alds[r * LDA + g * 8] = v;
    }
    __syncthreads();

    const int lane = tid & 63;
    const int wave = tid >> 6;
    const int m16 = lane & 15;
    const int quad = lane >> 4;

    f32x4 acc[8];
#pragma unroll
    for (int t = 0; t < 8; ++t) acc[t] = (f32x4){0.f, 0.f, 0.f, 0.f};

    const unsigned short* Abase = &Alds[(wave * 16 + m16) * LDA + quad * 8];
    const unsigned short* Wbase = &Wlds[m16 * LDA + quad * 8];
#pragma unroll
    for (int s = 0; s < 4; ++s) {
        short8 a = *(const short8*)&Abase[s * 32];
#pragma unroll
        for (int t = 0; t < 8; ++t) {
            short8 b = *(const short8*)&Wbase[t * 16 * LDA + s * 32];
            // swapped: W-frag is the A operand -> D[m=h][n=x-row]
            acc[t] = __builtin_amdgcn_mfma_f32_16x16x32_bf16(b, a, acc[t], 0, 0, 0);
        }
    }

    const int r = row0 + wave * 16 + m16;
    if (r < M) {
#pragma unroll
        for (int t = 0; t < 8; ++t) {
            ushort4 o;
            o.x = f2bf(acc[t][0] + bias[t * 16 + quad * 4 + 0]);
            o.y = f2bf(acc[t][1] + bias[t * 16 + quad * 4 + 1]);
            o.z = f2bf(acc[t][2] + bias[t * 16 + quad * 4 + 2]);
            o.w = f2bf(acc[t][3] + bias[t * 16 + quad * 4 + 3]);
            *(ushort4*)&C[(size_t)r * FDIM + t * 16 + quad * 4] = o;
        }
    }
}

// ---------------------------------------------------------------------------
// 4) layer-1 aggregation FUSED with the layer-2 GEMM — TWO NODES PER GROUP.
//    Rounds 4-7 lesson: the scheduler serializes any single dependent chain
//    regardless of source-level batching (predication / clamp / mem-clobber /
//    sched_barrier all left VGPR=40). So instead of instruction-level ILP we
//    use CHAIN-level ILP: each 16-lane group owns two nodes (A at base+gid,
//    B at base+16+gid); each loop iteration (2x unrolled) touches one edge of
//    each -> 4 data-independent row loads in flight that no scheduler can
//    serialize. Per-node FMA order stays ascending-k (numerics identical).
//    Clamped-index + zero-coef (proven r5-r7) keeps the loop branch-free.
__global__ __launch_bounds__(256) void agg_gemm2(const unsigned short* __restrict__ xw,
                                                 const float* __restrict__ dinv,
                                                 const int* __restrict__ start,
                                                 const int* __restrict__ cnt,
                                                 const int2* __restrict__ edata,
                                                 const float* __restrict__ bvec,
                                                 const unsigned short* __restrict__ WT2,
                                                 unsigned short* __restrict__ out,
                                                 int N) {
    const int base = blockIdx.x * 32;
    const int gid = threadIdx.x >> 4;   // 0..15
    const int l8 = threadIdx.x & 15;    // 8-col group
    const int na = base + gid;
    const int nb = base + 16 + gid;
    const bool aa = na < N, ab = nb < N;  // NO early return: __syncthreads below
    const int ia = aa ? na : (N - 1);
    const int ib = ab ? nb : (N - 1);

    const int ja = start[ia]; const int ca = aa ? cnt[ia] : 0;
    const int jb = start[ib]; const int cb = ab ? cnt[ib] : 0;
    float dva = dinv[ia], dvb = dinv[ib];
    float4 b0 = ((const float4*)bvec)[l8 * 2];
    float4 b1v = ((const float4*)bvec)[l8 * 2 + 1];
    short8 sva = *(const short8*)&xw[(size_t)ia * FDIM + l8 * 8];
    short8 svb = *(const short8*)&xw[(size_t)ib * FDIM + l8 * 8];

    float accA[8] = {b0.x, b0.y, b0.z, b0.w, b1v.x, b1v.y, b1v.z, b1v.w};
    float accB[8] = {b0.x, b0.y, b0.z, b0.w, b1v.x, b1v.y, b1v.z, b1v.w};
    bf8_fma(sva, dva * dva, accA);
    bf8_fma(svb, dvb * dvb, accB);

    const int jba = (ca > 0) ? ja : 0, cma = (ca > 0) ? ca - 1 : 0;
    const int jbb = (cb > 0) ? jb : 0, cmb = (cb > 0) ? cb - 1 : 0;
    const int cmax = max(ca, cb);
    for (int k = 0; k < cmax; k += 2) {
        int2 e0a = edata[jba + min(k, cma)];
        int2 e0b = edata[jbb + min(k, cmb)];
        int2 e1a = edata[jba + min(k + 1, cma)];
        int2 e1b = edata[jbb + min(k + 1, cmb)];
        short8 u0a = *(const short8*)&xw[(size_t)e0a.x * FDIM + l8 * 8];
        short8 u0b = *(const short8*)&xw[(size_t)e0b.x * FDIM + l8 * 8];
        short8 u1a = *(const short8*)&xw[(size_t)e1a.x * FDIM + l8 * 8];
        short8 u1b = *(const short8*)&xw[(size_t)e1b.x * FDIM + l8 * 8];
        bf8_fma(u0a, (k < ca) ? __int_as_float(e0a.y) : 0.f, accA);
        bf8_fma(u0b, (k < cb) ? __int_as_float(e0b.y) : 0.f, accB);
        bf8_fma(u1a, (k + 1 < ca) ? __int_as_float(e1a.y) : 0.f, accA);
        bf8_fma(u1b, (k + 1 < cb) ? __int_as_float(e1b.y) : 0.f, accB);
    }

    // relu + stage the 32x128 h1 tile (bf16) for the MFMA
    constexpr int LDH = 136;
    __shared__ unsigned short hlds[32 * LDH];  // 8.5 KiB
    {
        ushort4 o0, o1;
#pragma unroll
        for (int half = 0; half < 2; ++half) {
            const float* acc = half ? accB : accA;
            bool act = half ? ab : aa;
            if (act) {
                o0.x = f2bf(fmaxf(acc[0], 0.f)); o0.y = f2bf(fmaxf(acc[1], 0.f));
                o0.z = f2bf(fmaxf(acc[2], 0.f)); o0.w = f2bf(fmaxf(acc[3], 0.f));
                o1.x = f2bf(fmaxf(acc[4], 0.f)); o1.y = f2bf(fmaxf(acc[5], 0.f));
                o1.z = f2bf(fmaxf(acc[6], 0.f)); o1.w = f2bf(fmaxf(acc[7], 0.f));
            } else {
                o0.x = 0; o0.y = 0; o0.z = 0; o0.w = 0;
                o1.x = 0; o1.y = 0; o1.z = 0; o1.w = 0;
            }
            unsigned short* hp = &hlds[(half * 16 + gid) * LDH + l8 * 8];
            *(ushort4*)hp = o0;
            *(ushort4*)(hp + 4) = o1;
        }
    }
    __syncthreads();

    // swapped-operand MFMA: D[m=h][n=node]; wave w owns h-cols [w*32,+32),
    // two 16-row tiles per block.
    const int lane = threadIdx.x & 63;
    const int wave = threadIdx.x >> 6;
    const int m16 = lane & 15;
    const int quad = lane >> 4;
    const unsigned short* Wg = &WT2[(size_t)(wave * 32 + m16) * FDIM + quad * 8];
#pragma unroll
    for (int t = 0; t < 2; ++t) {
        f32x4 c0 = (f32x4){0.f, 0.f, 0.f, 0.f};
        f32x4 c1 = (f32x4){0.f, 0.f, 0.f, 0.f};
        const unsigned short* Abase = &hlds[(t * 16 + m16) * LDH + quad * 8];
#pragma unroll
        for (int s = 0; s < 4; ++s) {
            short8 a = *(const short8*)&Abase[s * 32];
            short8 w0 = *(const short8*)&Wg[s * 32];
            short8 w1 = *(const short8*)&Wg[16 * FDIM + s * 32];
            c0 = __builtin_amdgcn_mfma_f32_16x16x32_bf16(w0, a, c0, 0, 0, 0);
            c1 = __builtin_amdgcn_mfma_f32_16x16x32_bf16(w1, a, c1, 0, 0, 0);
        }
        const int r = base + t * 16 + m16;
        if (r < N) {
            ushort4 o;
            o.x = f2bf(c0[0]); o.y = f2bf(c0[1]); o.z = f2bf(c0[2]); o.w = f2bf(c0[3]);
            *(ushort4*)&out[(size_t)r * FDIM + wave * 32 + quad * 4] = o;
            o.x = f2bf(c1[0]); o.y = f2bf(c1[1]); o.z = f2bf(c1[2]); o.w = f2bf(c1[3]);
            *(ushort4*)&out[(size_t)r * FDIM + wave * 32 + 16 + quad * 4] = o;
        }
    }
}

// ---------------------------------------------------------------------------
// 5) layer-2 aggregation + pool — same two-node-per-group gather. Per-block
//    pool partial (32 rows) via plain LDS writes + tree reduce + one
//    coalesced 512B store (tag g0); boundary blocks (<64/6250) use direct
//    atomics (tag -1).
__global__ __launch_bounds__(256) void agg_pool(const unsigned short* __restrict__ xw,
                                                const float* __restrict__ dinv,
                                                const int* __restrict__ start,
                                                const int* __restrict__ cnt,
                                                const int2* __restrict__ edata,
                                                const float* __restrict__ bvec,
                                                const int* __restrict__ batch,
                                                float* __restrict__ pool_part,
                                                int* __restrict__ ptag,
                                                float* __restrict__ pooled, int N) {
    const int base = blockIdx.x * 32;
    const int gid = threadIdx.x >> 4;
    const int l8 = threadIdx.x & 15;
    const int na = base + gid;
    const int nb = base + 16 + gid;
    const bool aa = na < N, ab = nb < N;
    const int ia = aa ? na : (N - 1);
    const int ib = ab ? nb : (N - 1);

    const int ja = start[ia]; const int ca = aa ? cnt[ia] : 0;
    const int jb = start[ib]; const int cb = ab ? cnt[ib] : 0;
    float dva = dinv[ia], dvb = dinv[ib];
    float4 b0 = ((const float4*)bvec)[l8 * 2];
    float4 b1v = ((const float4*)bvec)[l8 * 2 + 1];
    short8 sva = *(const short8*)&xw[(size_t)ia * FDIM + l8 * 8];
    short8 svb = *(const short8*)&xw[(size_t)ib * FDIM + l8 * 8];

    float accA[8] = {b0.x, b0.y, b0.z, b0.w, b1v.x, b1v.y, b1v.z, b1v.w};
    float accB[8] = {b0.x, b0.y, b0.z, b0.w, b1v.x, b1v.y, b1v.z, b1v.w};
    bf8_fma(sva, dva * dva, accA);
    bf8_fma(svb, dvb * dvb, accB);

    const int jba = (ca > 0) ? ja : 0, cma = (ca > 0) ? ca - 1 : 0;
    const int jbb = (cb > 0) ? jb : 0, cmb = (cb > 0) ? cb - 1 : 0;
    const int cmax = max(ca, cb);
    for (int k = 0; k < cmax; k += 2) {
        int2 e0a = edata[jba + min(k, cma)];
        int2 e0b = edata[jbb + min(k, cmb)];
        int2 e1a = edata[jba + min(k + 1, cma)];
        int2 e1b = edata[jbb + min(k + 1, cmb)];
        short8 u0a = *(const short8*)&xw[(size_t)e0a.x * FDIM + l8 * 8];
        short8 u0b = *(const short8*)&xw[(size_t)e0b.x * FDIM + l8 * 8];
        short8 u1a = *(const short8*)&xw[(size_t)e1a.x * FDIM + l8 * 8];
        short8 u1b = *(const short8*)&xw[(size_t)e1b.x * FDIM + l8 * 8];
        bf8_fma(u0a, (k < ca) ? __int_as_float(e0a.y) : 0.f, accA);
        bf8_fma(u0b, (k < cb) ? __int_as_float(e0b.y) : 0.f, accB);
        bf8_fma(u1a, (k + 1 < ca) ? __int_as_float(e1a.y) : 0.f, accA);
        bf8_fma(u1b, (k + 1 < cb) ? __int_as_float(e1b.y) : 0.f, accB);
    }

    float rA[8], rB[8];
#pragma unroll
    for (int k = 0; k < 8; ++k) {
        rA[k] = aa ? fmaxf(accA[k], 0.f) : 0.f;
        rB[k] = ab ? fmaxf(accB[k], 0.f) : 0.f;
    }
    int g0 = batch[base];
    int g1 = batch[min(base + 31, N - 1)];
    if (g0 == g1) {  // block-uniform branch — safe around __syncthreads
        __shared__ float red[32][FDIM];  // 16 KB; plain writes, no LDS atomics
        float* dA = &red[gid][l8 * 8];
        *(float4*)dA = make_float4(rA[0], rA[1], rA[2], rA[3]);
        *(float4*)(dA + 4) = make_float4(rA[4], rA[5], rA[6], rA[7]);
        float* dB = &red[16 + gid][l8 * 8];
        *(float4*)dB = make_float4(rB[0], rB[1], rB[2], rB[3]);
        *(float4*)(dB + 4) = make_float4(rB[4], rB[5], rB[6], rB[7]);
        __syncthreads();
        if (threadIdx.x < FDIM) {
            float s = 0.f;
#pragma unroll
            for (int i = 0; i < 32; ++i) s += red[i][threadIdx.x];
            pool_part[(size_t)blockIdx.x * FDIM + threadIdx.x] = s;
            if (threadIdx.x == 0) ptag[blockIdx.x] = g0;
        }
    } else {  // rare boundary block: direct atomics, slot skipped
        if (threadIdx.x == 0) ptag[blockIdx.x] = -1;
        if (aa) {
            int g = batch[na];
#pragma unroll
            for (int k = 0; k < 8; ++k)
                unsafeAtomicAdd(&pooled[g * FDIM + l8 * 8 + k], rA[k]);
        }
        if (ab) {
            int g = batch[nb];
#pragma unroll
            for (int k = 0; k < 8; ++k)
                unsafeAtomicAdd(&pooled[g * FDIM + l8 * 8 + k], rB[k]);
        }
    }
}

// ---------------------------------------------------------------------------
// 6) reduce tagged per-block pool partials into d_out (tags monotone).
__global__ __launch_bounds__(128) void pool_reduce(const float* __restrict__ pool_part,
                                                   const int* __restrict__ ptag,
                                                   int nslots, float* __restrict__ out) {
    int per = (nslots + gridDim.x - 1) / gridDim.x;
    int s0 = blockIdx.x * per;
    int s1 = min(s0 + per, nslots);
    int t = threadIdx.x;
    float acc = 0.f;
    int cur = -1;
    for (int s = s0; s < s1; ++s) {
        int g = ptag[s];  // broadcast scalar load
        if (g < 0) continue;
        if (g != cur) {
            if (cur >= 0) unsafeAtomicAdd(&out[cur * FDIM + t], acc);
            acc = 0.f;
            cur = g;
        }
        acc += pool_part[(size_t)s * FDIM + t];
    }
    if (cur >= 0) unsafeAtomicAdd(&out[cur * FDIM + t], acc);
}

// ---------------------------------------------------------------------------
extern "C" void kernel_launch(void* const* d_in, const int* in_sizes, int n_in,
                              void* d_out, int out_size, void* d_ws, size_t ws_size,
                              hipStream_t stream) {
    const float* x = (const float*)d_in[0];
    const int* ei = (const int*)d_in[1];
    const int* batch = (const int*)d_in[2];
    const float* W1 = (const float*)d_in[4];
    const float* b1 = (const float*)d_in[5];
    const float* W2 = (const float*)d_in[6];
    const float* b2 = (const float*)d_in[7];

    const int N = in_sizes[2];
    const int E = in_sizes[1] / 2;
    const int* srcp = ei;
    const int* dstp = ei + E;

    const size_t NF = (size_t)N * FDIM;
    const int aggGrid = (N + 31) / 32;  // 32 nodes per block now
    unsigned short* bufA = (unsigned short*)d_ws;  // N*128 bf16 (xw)
    unsigned short* bufB = bufA + NF;              // N*128 bf16 (x_bf16, then h1@W2)
    int* cnt = (int*)(bufB + NF);                  // N      <- memset from here
    int* counter = cnt + N;                        // 4
    float* bias0 = (float*)(counter + 4);          // 128    <- memset to here
    float* dinv = bias0 + FDIM;                    // N
    int* start = (int*)(dinv + N);                 // N
    int* wcur = start + N;                         // N
    unsigned short* WT1 = (unsigned short*)(wcur + N);  // 128*128 bf16
    unsigned short* WT2 = WT1 + FDIM * FDIM;            // 128*128 bf16
    int2* edata = (int2*)(WT2 + FDIM * FDIM);      // E x {src, coef}
    float* pool_part = (float*)(edata + E);        // aggGrid*128 f32
    int* ptag = (int*)(pool_part + (size_t)aggGrid * FDIM);  // aggGrid
    float* partials = (float*)edata;               // aliased; dead before gemm1_fill
    const int STAT_BLOCKS = 512;

    hipMemsetAsync(cnt, 0, ((size_t)N + 4 + FDIM) * sizeof(int), stream);
    hipMemsetAsync(d_out, 0, (size_t)out_size * sizeof(float), stream);

    const int degBlocks = (E + 255) / 256;
    const int offsBlocks = (N + 255) / 256;
    const int gemmGrid = (N + 63) / 64;

    // pre_combo also emits bf16 cast of x into bufB (dead until agg_gemm2
    // overwrites it) — gemm1_fill then reads 51 MB instead of 102 MB.
    pre_combo<<<STAT_BLOCKS + degBlocks, 256, 0, stream>>>(x, N, partials, STAT_BLOCKS,
                                                           dstp, E, cnt, bufB);
    mid_combo<<<offsBlocks + 16, 256, 0, stream>>>(cnt, N, start, wcur, counter, dinv,
                                                   partials, STAT_BLOCKS, offsBlocks,
                                                   W1, W2, WT1, WT2, bias0);

    // ---- layer 1 GEMM (reads x_bf16) + edge bucketing overlapped
    gemm1_fill<<<gemmGrid + degBlocks, 256, 0, stream>>>(bufB, WT1, bias0, bufA, N,
                                                         gemmGrid, srcp, dstp, dinv,
                                                         wcur, edata, E);

    // ---- layer-1 aggregate + layer-2 GEMM fused (h1 never hits HBM)
    agg_gemm2<<<aggGrid, 256, 0, stream>>>(bufA, dinv, start, cnt, edata, b1, WT2,
                                           bufB, N);

    // ---- layer-2 aggregate + pool fused (h2 never materialized)
    agg_pool<<<aggGrid, 256, 0, stream>>>(bufB, dinv, start, cnt, edata, b2,
                                          batch, pool_part, ptag, (float*)d_out, N);
    pool_reduce<<<256, 128, 0, stream>>>(pool_part, ptag, aggGrid, (float*)d_out);
}